// Round 1
// baseline (9147.387 us; speedup 1.0000x reference)
//
#include <hip/hip_runtime.h>

#define NT 64
#define NB 262144

struct P {
  const float* node_feat; const float* edge_feat; const int* ei;
  const float* W_ne; const float* b_ne; const float* g_ne; const float* be_ne;
  const float* W_ee; const float* b_ee;
  const float* msg_W1; const float* msg_b1; const float* msg_W2; const float* msg_b2;
  const float* upd_W1; const float* upd_b1; const float* upd_g1; const float* upd_be1;
  const float* upd_W2; const float* upd_b2; const float* upd_g2; const float* upd_be2;
  const float* Wp; const float* bp; const float* gp; const float* bep;
  const float* mW1; const float* mb1; const float* mg1; const float* mbe1;
  const float* mW2; const float* mb2; const float* mg2; const float* mbe2;
  const float* mW3; const float* mb3; const float* mg3; const float* mbe3;
  const float* mW4; const float* mb4;
  float* out;
};

__device__ __forceinline__ float sigm(float x) {
  return __builtin_amdgcn_rcpf(1.0f + __expf(-x));
}

__device__ __forceinline__ void add16(float (&a)[16], const float (&m)[16]) {
#pragma unroll
  for (int d = 0; d < 16; d++) a[d] += m[d];
}

__device__ __forceinline__ void cp16(float (&dst)[16], const float (&src)[16]) {
#pragma unroll
  for (int d = 0; d < 16; d++) dst[d] = src[d];
}

// 1/sqrt(1+1e-5)
#define INVC 0.9999950000374997f

__global__ __launch_bounds__(NT) void gnn_kernel(P p) {
  const int t = threadIdx.x;
  const int g = blockIdx.x * NT + t;

  // column-per-thread scratch: rows 0..79 = x[n][d] (n*16+d), rows 80..95 = raw edge_feat
  __shared__ float xs[96][NT];

  // ---------------- node encoder: x = bn5(node_feat @ W_ne + b_ne) ----------------
#pragma unroll
  for (int n = 0; n < 5; n++) {
    float nfv[7];
#pragma unroll
    for (int k = 0; k < 7; k++) nfv[k] = p.node_feat[(size_t)g * 35 + n * 7 + k];
    const float gn = p.g_ne[n] * INVC;
    const float bn_ = p.be_ne[n];
#pragma unroll
    for (int d = 0; d < 16; d++) {
      float a = p.b_ne[d];
#pragma unroll
      for (int k = 0; k < 7; k++) a = fmaf(nfv[k], p.W_ne[k * 16 + d], a);
      xs[n * 16 + d][t] = fmaf(gn, a, bn_);
    }
  }

  // ---------------- raw edge features -> LDS (vectorized, 64B-aligned) ----------------
  {
    const float4* efv = reinterpret_cast<const float4*>(p.edge_feat + (size_t)g * 16);
#pragma unroll
    for (int q = 0; q < 4; q++) {
      float4 v = efv[q];
      xs[80 + q * 4 + 0][t] = v.x;
      xs[80 + q * 4 + 1][t] = v.y;
      xs[80 + q * 4 + 2][t] = v.z;
      xs[80 + q * 4 + 3][t] = v.w;
    }
  }

  float agg[5][16];

  // ---------------- L message-passing layers ----------------
#pragma unroll 1
  for (int l = 0; l < 4; l++) {
    const float* mW1 = p.msg_W1 + l * 576;
    const float* mb1 = p.msg_b1 + l * 16;
    const float* mW2 = p.msg_W2 + l * 256;
    const float* mb2 = p.msg_b2 + l * 16;
    const float* uW1 = p.upd_W1 + l * 512;
    const float* ub1 = p.upd_b1 + l * 16;
    const float* ug1 = p.upd_g1 + l * 5;
    const float* ube1 = p.upd_be1 + l * 5;
    const float* uW2 = p.upd_W2 + l * 256;
    const float* ub2 = p.upd_b2 + l * 16;
    const float* ug2 = p.upd_g2 + l * 5;
    const float* ube2 = p.upd_be2 + l * 5;

#pragma unroll
    for (int n = 0; n < 5; n++)
#pragma unroll
      for (int d = 0; d < 16; d++) agg[n][d] = 0.f;

    // ---- phase A: per-edge messages, scatter-add into agg[dst] ----
#pragma unroll 1
    for (int e = 0; e < 8; e++) {
      const int se = p.ei[e];      // src (uniform scalar)
      const int de = p.ei[8 + e];  // dst (uniform scalar)

      float m1[16];
#pragma unroll
      for (int d = 0; d < 16; d++) m1[d] = mb1[d];

      // h_i = x[dst] part (k = 0..15)
#pragma unroll
      for (int k = 0; k < 16; k++) {
        float hv = xs[de * 16 + k][t];
#pragma unroll
        for (int d = 0; d < 16; d++) m1[d] = fmaf(hv, mW1[k * 16 + d], m1[d]);
      }
      // h_j = x[src] part (k = 16..31)
#pragma unroll
      for (int k = 0; k < 16; k++) {
        float hv = xs[se * 16 + k][t];
#pragma unroll
        for (int d = 0; d < 16; d++) m1[d] = fmaf(hv, mW1[(16 + k) * 16 + d], m1[d]);
      }
      // ea part (k = 32..35), ea recomputed from raw edge features
      {
        float e0 = xs[80 + e * 2 + 0][t];
        float e1 = xs[80 + e * 2 + 1][t];
#pragma unroll
        for (int j = 0; j < 4; j++) {
          float ea = fmaf(e0, p.W_ee[j], fmaf(e1, p.W_ee[4 + j], p.b_ee[j]));
#pragma unroll
          for (int d = 0; d < 16; d++) m1[d] = fmaf(ea, mW1[(32 + j) * 16 + d], m1[d]);
        }
      }
#pragma unroll
      for (int d = 0; d < 16; d++) m1[d] = sigm(m1[d]);

      float m2[16];
#pragma unroll
      for (int d = 0; d < 16; d++) {
        float a = mb2[d];
#pragma unroll
        for (int k = 0; k < 16; k++) a = fmaf(m1[k], mW2[k * 16 + d], a);
        m2[d] = sigm(a);
      }

      // uniform-branch scatter (keeps agg in registers, no scratch)
      if (de == 0) add16(agg[0], m2);
      else if (de == 1) add16(agg[1], m2);
      else if (de == 2) add16(agg[2], m2);
      else if (de == 3) add16(agg[3], m2);
      else add16(agg[4], m2);
    }

    // ---- phase B: per-node update, x[n] += u2 (in place; updates don't feed each other) ----
#pragma unroll 1
    for (int n = 0; n < 5; n++) {
      float cntf = 0.f;
#pragma unroll
      for (int e = 0; e < 8; e++) cntf += (p.ei[8 + e] == n) ? 1.f : 0.f;
      const float dr = 1.0f / fmaxf(cntf, 1.0f);

      float a16[16];
      if (n == 0) cp16(a16, agg[0]);
      else if (n == 1) cp16(a16, agg[1]);
      else if (n == 2) cp16(a16, agg[2]);
      else if (n == 3) cp16(a16, agg[3]);
      else cp16(a16, agg[4]);

      float acc[16];
#pragma unroll
      for (int d = 0; d < 16; d++) acc[d] = ub1[d];
#pragma unroll
      for (int k = 0; k < 16; k++) {
        float xv = xs[n * 16 + k][t];
#pragma unroll
        for (int d = 0; d < 16; d++) acc[d] = fmaf(xv, uW1[k * 16 + d], acc[d]);
      }
#pragma unroll
      for (int k = 0; k < 16; k++) {
        float av = a16[k] * dr;
#pragma unroll
        for (int d = 0; d < 16; d++) acc[d] = fmaf(av, uW1[(16 + k) * 16 + d], acc[d]);
      }
      const float G1 = ug1[n] * INVC;
      const float B1 = ube1[n];
      float u1[16];
#pragma unroll
      for (int d = 0; d < 16; d++) u1[d] = sigm(fmaf(G1, acc[d], B1));

      const float G2 = ug2[n] * INVC;
      const float B2 = ube2[n];
#pragma unroll
      for (int d = 0; d < 16; d++) {
        float a = ub2[d];
#pragma unroll
        for (int k = 0; k < 16; k++) a = fmaf(u1[k], uW2[k * 16 + d], a);
        float u2 = sigm(fmaf(G2, a, B2));
        xs[n * 16 + d][t] += u2;
      }
    }
  }

  // ---------------- pooling: p1 = sigmoid(bnc(x.reshape(80) @ Wp + bp)) ----------------
  float p1[16];
  {
    float acc[16];
#pragma unroll
    for (int d = 0; d < 16; d++) acc[d] = p.bp[d];
#pragma unroll 1
    for (int k = 0; k < 80; k++) {
      float xv = xs[k][t];
#pragma unroll
      for (int d = 0; d < 16; d++) acc[d] = fmaf(xv, p.Wp[k * 16 + d], acc[d]);
    }
#pragma unroll
    for (int d = 0; d < 16; d++)
      p1[d] = sigm(fmaf(p.gp[d] * INVC, acc[d], p.bep[d]));
  }

  // ---------------- MLP head ----------------
  // mlp1: 16 -> 64, result into xs rows 0..63
  {
#pragma unroll
    for (int d = 0; d < 64; d++) {
      float a = p.mb1[d];
#pragma unroll
      for (int k = 0; k < 16; k++) a = fmaf(p1[k], p.mW1[k * 64 + d], a);
      xs[d][t] = sigm(fmaf(p.mg1[d] * INVC, a, p.mbe1[d]));
    }
  }
  // mlp2: 64 -> 64
  {
    float acc[64];
#pragma unroll
    for (int d = 0; d < 64; d++) acc[d] = p.mb2[d];
#pragma unroll 1
    for (int k = 0; k < 64; k++) {
      float hv = xs[k][t];
#pragma unroll
      for (int d = 0; d < 64; d++) acc[d] = fmaf(hv, p.mW2[k * 64 + d], acc[d]);
    }
#pragma unroll
    for (int d = 0; d < 64; d++) xs[d][t] = sigm(fmaf(p.mg2[d] * INVC, acc[d], p.mbe2[d]));
  }
  // mlp3: 64 -> 64
  {
    float acc[64];
#pragma unroll
    for (int d = 0; d < 64; d++) acc[d] = p.mb3[d];
#pragma unroll 1
    for (int k = 0; k < 64; k++) {
      float hv = xs[k][t];
#pragma unroll
      for (int d = 0; d < 64; d++) acc[d] = fmaf(hv, p.mW3[k * 64 + d], acc[d]);
    }
#pragma unroll
    for (int d = 0; d < 64; d++) xs[d][t] = sigm(fmaf(p.mg3[d] * INVC, acc[d], p.mbe3[d]));
  }
  // mlp4: 64 -> 1
  {
    float a = p.mb4[0];
#pragma unroll 1
    for (int k = 0; k < 64; k++) a = fmaf(xs[k][t], p.mW4[k], a);
    p.out[g] = a;
  }
}

extern "C" void kernel_launch(void* const* d_in, const int* in_sizes, int n_in,
                              void* d_out, int out_size, void* d_ws, size_t ws_size,
                              hipStream_t stream) {
  P p;
  p.node_feat = (const float*)d_in[0];
  p.edge_feat = (const float*)d_in[1];
  p.ei        = (const int*)d_in[2];
  p.W_ne  = (const float*)d_in[3];  p.b_ne  = (const float*)d_in[4];
  p.g_ne  = (const float*)d_in[5];  p.be_ne = (const float*)d_in[6];
  p.W_ee  = (const float*)d_in[7];  p.b_ee  = (const float*)d_in[8];
  p.msg_W1 = (const float*)d_in[9];  p.msg_b1 = (const float*)d_in[10];
  p.msg_W2 = (const float*)d_in[11]; p.msg_b2 = (const float*)d_in[12];
  p.upd_W1 = (const float*)d_in[13]; p.upd_b1 = (const float*)d_in[14];
  p.upd_g1 = (const float*)d_in[15]; p.upd_be1 = (const float*)d_in[16];
  p.upd_W2 = (const float*)d_in[17]; p.upd_b2 = (const float*)d_in[18];
  p.upd_g2 = (const float*)d_in[19]; p.upd_be2 = (const float*)d_in[20];
  p.Wp  = (const float*)d_in[21]; p.bp  = (const float*)d_in[22];
  p.gp  = (const float*)d_in[23]; p.bep = (const float*)d_in[24];
  p.mW1 = (const float*)d_in[25]; p.mb1 = (const float*)d_in[26];
  p.mg1 = (const float*)d_in[27]; p.mbe1 = (const float*)d_in[28];
  p.mW2 = (const float*)d_in[29]; p.mb2 = (const float*)d_in[30];
  p.mg2 = (const float*)d_in[31]; p.mbe2 = (const float*)d_in[32];
  p.mW3 = (const float*)d_in[33]; p.mb3 = (const float*)d_in[34];
  p.mg3 = (const float*)d_in[35]; p.mbe3 = (const float*)d_in[36];
  p.mW4 = (const float*)d_in[37]; p.mb4 = (const float*)d_in[38];
  p.out = (float*)d_out;

  hipLaunchKernelGGL(gnn_kernel, dim3(NB / NT), dim3(NT), 0, stream, p);
}

// Round 2
// 2350.390 us; speedup vs baseline: 3.8919x; 3.8919x over previous
//
#include <hip/hip_runtime.h>

#define NT 64
#define NB 262144

struct P {
  const float* node_feat; const float* edge_feat; const int* ei;
  const float* W_ne; const float* b_ne; const float* g_ne; const float* be_ne;
  const float* W_ee; const float* b_ee;
  const float* msg_W1; const float* msg_b1; const float* msg_W2; const float* msg_b2;
  const float* upd_W1; const float* upd_b1; const float* upd_g1; const float* upd_be1;
  const float* upd_W2; const float* upd_b2; const float* upd_g2; const float* upd_be2;
  const float* Wp; const float* bp; const float* gp; const float* bep;
  const float* mW1; const float* mb1; const float* mg1; const float* mbe1;
  const float* mW2; const float* mb2; const float* mg2; const float* mbe2;
  const float* mW3; const float* mb3; const float* mg3; const float* mbe3;
  const float* mW4; const float* mb4;
  float* out;
};

__device__ __forceinline__ float sigm(float x) {
  return __builtin_amdgcn_rcpf(1.0f + __expf(-x));
}

__device__ __forceinline__ void add16(float (&a)[16], const float (&m)[16]) {
#pragma unroll
  for (int d = 0; d < 16; d++) a[d] += m[d];
}

__device__ __forceinline__ void cp16(float (&dst)[16], const float (&src)[16]) {
#pragma unroll
  for (int d = 0; d < 16; d++) dst[d] = src[d];
}

// 1/sqrt(1+1e-5)
#define INVC 0.9999950000374997f

// LDS layout (column-per-thread, bank-conflict-free, zero barriers):
//   rows  0..79 : x[n][d] = row n*16+d          (graph state)
//   rows 80..95 : raw edge_feat (16 floats)
//   rows  0..63 / 64..127 : MLP ping-pong after the GNN layers
__global__ __launch_bounds__(NT, 1) void gnn_kernel(P p) {
  const int t = threadIdx.x;
  const int g = blockIdx.x * NT + t;

  __shared__ float xs[128][NT];

  // edge indices -> guaranteed SGPRs
  // (we index them only with compile-time constants below)
  // ---------------- node encoder: x = bn5(node_feat @ W_ne + b_ne) ----------------
#pragma unroll
  for (int n = 0; n < 5; n++) {
    float nfv[7];
#pragma unroll
    for (int k = 0; k < 7; k++) nfv[k] = p.node_feat[(size_t)g * 35 + n * 7 + k];
    const float gn = p.g_ne[n] * INVC;
    const float bn_ = p.be_ne[n];
#pragma unroll
    for (int d = 0; d < 16; d++) {
      float a = p.b_ne[d];
#pragma unroll
      for (int k = 0; k < 7; k++) a = fmaf(nfv[k], p.W_ne[k * 16 + d], a);
      xs[n * 16 + d][t] = fmaf(gn, a, bn_);
    }
  }

  // ---------------- raw edge features -> LDS (vectorized) ----------------
  {
    const float4* efv = reinterpret_cast<const float4*>(p.edge_feat + (size_t)g * 16);
#pragma unroll
    for (int q = 0; q < 4; q++) {
      float4 v = efv[q];
      xs[80 + q * 4 + 0][t] = v.x;
      xs[80 + q * 4 + 1][t] = v.y;
      xs[80 + q * 4 + 2][t] = v.z;
      xs[80 + q * 4 + 3][t] = v.w;
    }
  }

  float agg[5][16];

  // ---------------- L message-passing layers ----------------
#pragma unroll 1
  for (int l = 0; l < 4; l++) {
    const float* mW1 = p.msg_W1 + l * 576;
    const float* mb1 = p.msg_b1 + l * 16;
    const float* mW2 = p.msg_W2 + l * 256;
    const float* mb2 = p.msg_b2 + l * 16;
    const float* uW1 = p.upd_W1 + l * 512;
    const float* ub1 = p.upd_b1 + l * 16;
    const float* ug1 = p.upd_g1 + l * 5;
    const float* ube1 = p.upd_be1 + l * 5;
    const float* uW2 = p.upd_W2 + l * 256;
    const float* ub2 = p.upd_b2 + l * 16;
    const float* ug2 = p.upd_g2 + l * 5;
    const float* ube2 = p.upd_be2 + l * 5;

#pragma unroll
    for (int n = 0; n < 5; n++)
#pragma unroll
      for (int d = 0; d < 16; d++) agg[n][d] = 0.f;

    // ---- phase A: per-edge messages, scatter-add into agg[dst] ----
#pragma unroll 1
    for (int e = 0; e < 8; e++) {
      const int se = __builtin_amdgcn_readfirstlane(p.ei[e]);      // src (SGPR)
      const int de = __builtin_amdgcn_readfirstlane(p.ei[8 + e]);  // dst (SGPR)

      float m1[16];
#pragma unroll
      for (int d = 0; d < 16; d++) m1[d] = mb1[d];

      // h_i = x[dst] part (k = 0..15)
#pragma unroll 4
      for (int k = 0; k < 16; k++) {
        float hv = xs[de * 16 + k][t];
#pragma unroll
        for (int d = 0; d < 16; d++) m1[d] = fmaf(hv, mW1[k * 16 + d], m1[d]);
      }
      // h_j = x[src] part (k = 16..31)
#pragma unroll 4
      for (int k = 0; k < 16; k++) {
        float hv = xs[se * 16 + k][t];
#pragma unroll
        for (int d = 0; d < 16; d++) m1[d] = fmaf(hv, mW1[(16 + k) * 16 + d], m1[d]);
      }
      // ea part (k = 32..35), ea recomputed from raw edge features
      {
        float e0 = xs[80 + e * 2 + 0][t];
        float e1 = xs[80 + e * 2 + 1][t];
#pragma unroll
        for (int j = 0; j < 4; j++) {
          float ea = fmaf(e0, p.W_ee[j], fmaf(e1, p.W_ee[4 + j], p.b_ee[j]));
#pragma unroll
          for (int d = 0; d < 16; d++) m1[d] = fmaf(ea, mW1[(32 + j) * 16 + d], m1[d]);
        }
      }
#pragma unroll
      for (int d = 0; d < 16; d++) m1[d] = sigm(m1[d]);

      float m2[16];
#pragma unroll
      for (int d = 0; d < 16; d++) {
        float a = mb2[d];
#pragma unroll
        for (int k = 0; k < 16; k++) a = fmaf(m1[k], mW2[k * 16 + d], a);
        m2[d] = sigm(a);
      }

      // uniform-branch scatter (keeps agg in registers, static indices only)
      if (de == 0) add16(agg[0], m2);
      else if (de == 1) add16(agg[1], m2);
      else if (de == 2) add16(agg[2], m2);
      else if (de == 3) add16(agg[3], m2);
      else add16(agg[4], m2);
    }

    // ---- phase B: per-node update, x[n] += u2 (in place) ----
#pragma unroll 1
    for (int n = 0; n < 5; n++) {
      float cntf = 0.f;
#pragma unroll
      for (int e = 0; e < 8; e++)
        cntf += (__builtin_amdgcn_readfirstlane(p.ei[8 + e]) == n) ? 1.f : 0.f;
      const float dr = 1.0f / fmaxf(cntf, 1.0f);

      float a16[16];
      if (n == 0) cp16(a16, agg[0]);
      else if (n == 1) cp16(a16, agg[1]);
      else if (n == 2) cp16(a16, agg[2]);
      else if (n == 3) cp16(a16, agg[3]);
      else cp16(a16, agg[4]);

      float acc[16];
#pragma unroll
      for (int d = 0; d < 16; d++) acc[d] = ub1[d];
#pragma unroll 4
      for (int k = 0; k < 16; k++) {
        float xv = xs[n * 16 + k][t];
#pragma unroll
        for (int d = 0; d < 16; d++) acc[d] = fmaf(xv, uW1[k * 16 + d], acc[d]);
      }
#pragma unroll 4
      for (int k = 0; k < 16; k++) {
        float av = a16[k] * dr;
#pragma unroll
        for (int d = 0; d < 16; d++) acc[d] = fmaf(av, uW1[(16 + k) * 16 + d], acc[d]);
      }
      const float G1 = ug1[n] * INVC;
      const float B1 = ube1[n];
      float u1[16];
#pragma unroll
      for (int d = 0; d < 16; d++) u1[d] = sigm(fmaf(G1, acc[d], B1));

      const float G2 = ug2[n] * INVC;
      const float B2 = ube2[n];
#pragma unroll
      for (int d = 0; d < 16; d++) {
        float a = ub2[d];
#pragma unroll
        for (int k = 0; k < 16; k++) a = fmaf(u1[k], uW2[k * 16 + d], a);
        float u2 = sigm(fmaf(G2, a, B2));
        xs[n * 16 + d][t] += u2;
      }
    }
  }

  // ---------------- pooling: p1 = sigmoid(bnc(x.reshape(80) @ Wp + bp)) ----------------
  float p1[16];
  {
    float acc[16];
#pragma unroll
    for (int d = 0; d < 16; d++) acc[d] = p.bp[d];
#pragma unroll 4
    for (int k = 0; k < 80; k++) {
      float xv = xs[k][t];
#pragma unroll
      for (int d = 0; d < 16; d++) acc[d] = fmaf(xv, p.Wp[k * 16 + d], acc[d]);
    }
#pragma unroll
    for (int d = 0; d < 16; d++)
      p1[d] = sigm(fmaf(p.gp[d] * INVC, acc[d], p.bep[d]));
  }

  // ---------------- MLP head, chunked 16-wide, LDS ping-pong ----------------
  // mlp1: 16 -> 64 (p1 regs -> rows 0..63)
#pragma unroll 1
  for (int c = 0; c < 4; c++) {
    float acc[16];
#pragma unroll
    for (int d = 0; d < 16; d++) acc[d] = p.mb1[c * 16 + d];
#pragma unroll 4
    for (int k = 0; k < 16; k++) {
      float hv = p1[k];
#pragma unroll
      for (int d = 0; d < 16; d++) acc[d] = fmaf(hv, p.mW1[k * 64 + c * 16 + d], acc[d]);
    }
#pragma unroll
    for (int d = 0; d < 16; d++)
      xs[c * 16 + d][t] = sigm(fmaf(p.mg1[c * 16 + d] * INVC, acc[d], p.mbe1[c * 16 + d]));
  }
  // mlp2: 64 -> 64 (rows 0..63 -> rows 64..127)
#pragma unroll 1
  for (int c = 0; c < 4; c++) {
    float acc[16];
#pragma unroll
    for (int d = 0; d < 16; d++) acc[d] = p.mb2[c * 16 + d];
#pragma unroll 4
    for (int k = 0; k < 64; k++) {
      float hv = xs[k][t];
#pragma unroll
      for (int d = 0; d < 16; d++) acc[d] = fmaf(hv, p.mW2[k * 64 + c * 16 + d], acc[d]);
    }
#pragma unroll
    for (int d = 0; d < 16; d++)
      xs[64 + c * 16 + d][t] = sigm(fmaf(p.mg2[c * 16 + d] * INVC, acc[d], p.mbe2[c * 16 + d]));
  }
  // mlp3: 64 -> 64 (rows 64..127 -> rows 0..63)
#pragma unroll 1
  for (int c = 0; c < 4; c++) {
    float acc[16];
#pragma unroll
    for (int d = 0; d < 16; d++) acc[d] = p.mb3[c * 16 + d];
#pragma unroll 4
    for (int k = 0; k < 64; k++) {
      float hv = xs[64 + k][t];
#pragma unroll
      for (int d = 0; d < 16; d++) acc[d] = fmaf(hv, p.mW3[k * 64 + c * 16 + d], acc[d]);
    }
#pragma unroll
    for (int d = 0; d < 16; d++)
      xs[c * 16 + d][t] = sigm(fmaf(p.mg3[c * 16 + d] * INVC, acc[d], p.mbe3[c * 16 + d]));
  }
  // mlp4: 64 -> 1 (rows 0..63 -> out)
  {
    float a = p.mb4[0];
#pragma unroll 4
    for (int k = 0; k < 64; k++) a = fmaf(xs[k][t], p.mW4[k], a);
    p.out[g] = a;
  }
}

extern "C" void kernel_launch(void* const* d_in, const int* in_sizes, int n_in,
                              void* d_out, int out_size, void* d_ws, size_t ws_size,
                              hipStream_t stream) {
  P p;
  p.node_feat = (const float*)d_in[0];
  p.edge_feat = (const float*)d_in[1];
  p.ei        = (const int*)d_in[2];
  p.W_ne  = (const float*)d_in[3];  p.b_ne  = (const float*)d_in[4];
  p.g_ne  = (const float*)d_in[5];  p.be_ne = (const float*)d_in[6];
  p.W_ee  = (const float*)d_in[7];  p.b_ee  = (const float*)d_in[8];
  p.msg_W1 = (const float*)d_in[9];  p.msg_b1 = (const float*)d_in[10];
  p.msg_W2 = (const float*)d_in[11]; p.msg_b2 = (const float*)d_in[12];
  p.upd_W1 = (const float*)d_in[13]; p.upd_b1 = (const float*)d_in[14];
  p.upd_g1 = (const float*)d_in[15]; p.upd_be1 = (const float*)d_in[16];
  p.upd_W2 = (const float*)d_in[17]; p.upd_b2 = (const float*)d_in[18];
  p.upd_g2 = (const float*)d_in[19]; p.upd_be2 = (const float*)d_in[20];
  p.Wp  = (const float*)d_in[21]; p.bp  = (const float*)d_in[22];
  p.gp  = (const float*)d_in[23]; p.bep = (const float*)d_in[24];
  p.mW1 = (const float*)d_in[25]; p.mb1 = (const float*)d_in[26];
  p.mg1 = (const float*)d_in[27]; p.mbe1 = (const float*)d_in[28];
  p.mW2 = (const float*)d_in[29]; p.mb2 = (const float*)d_in[30];
  p.mg2 = (const float*)d_in[31]; p.mbe2 = (const float*)d_in[32];
  p.mW3 = (const float*)d_in[33]; p.mb3 = (const float*)d_in[34];
  p.mg3 = (const float*)d_in[35]; p.mbe3 = (const float*)d_in[36];
  p.mW4 = (const float*)d_in[37]; p.mb4 = (const float*)d_in[38];
  p.out = (float*)d_out;

  hipLaunchKernelGGL(gnn_kernel, dim3(NB / NT), dim3(NT), 0, stream, p);
}

// Round 3
// 1935.103 us; speedup vs baseline: 4.7271x; 1.2146x over previous
//
#include <hip/hip_runtime.h>

#define NT 64
#define NB 262144

struct P {
  const float* node_feat; const float* edge_feat; const int* ei;
  const float* W_ne; const float* b_ne; const float* g_ne; const float* be_ne;
  const float* W_ee; const float* b_ee;
  const float* msg_W1; const float* msg_b1; const float* msg_W2; const float* msg_b2;
  const float* upd_W1; const float* upd_b1; const float* upd_g1; const float* upd_be1;
  const float* upd_W2; const float* upd_b2; const float* upd_g2; const float* upd_be2;
  const float* Wp; const float* bp; const float* gp; const float* bep;
  const float* mW1; const float* mb1; const float* mg1; const float* mbe1;
  const float* mW2; const float* mb2; const float* mg2; const float* mbe2;
  const float* mW3; const float* mb3; const float* mg3; const float* mbe3;
  const float* mW4; const float* mb4;
  float* out;
};

__device__ __forceinline__ float sigm(float x) {
  return __builtin_amdgcn_rcpf(1.0f + __expf(-x));
}

// 1/sqrt(1+1e-5)
#define INVC 0.9999950000374997f

// LDS layout (column-per-thread xs[row][t]: bank = t%32, 2 lanes/bank = free,
// zero barriers, every row index may be runtime — LDS addressing is happy):
//   rows   0..79  : x[n][d] = row n*16+d       (graph state)
//   rows  80..95  : raw edge_feat (16 floats)
//   rows  96..175 : agg[n][d] = row 96+n*16+d  (message accumulators)
//   MLP phase reuse: ping A = rows 0..63, ping B = rows 96..159
__global__ __launch_bounds__(NT, 1) void gnn_kernel(P p) {
  const int t = threadIdx.x;
  const int g = blockIdx.x * NT + t;

  __shared__ float xs[176][NT];

  // ---------------- node encoder: x = bn5(node_feat @ W_ne + b_ne) ----------------
#pragma unroll
  for (int n = 0; n < 5; n++) {
    float nfv[7];
#pragma unroll
    for (int k = 0; k < 7; k++) nfv[k] = p.node_feat[(size_t)g * 35 + n * 7 + k];
    const float gn = p.g_ne[n] * INVC;
    const float bn_ = p.be_ne[n];
#pragma unroll
    for (int d = 0; d < 16; d++) {
      float a = p.b_ne[d];
#pragma unroll
      for (int k = 0; k < 7; k++) a = fmaf(nfv[k], p.W_ne[k * 16 + d], a);
      xs[n * 16 + d][t] = fmaf(gn, a, bn_);
    }
  }

  // ---------------- raw edge features -> LDS (vectorized) ----------------
  {
    const float4* efv = reinterpret_cast<const float4*>(p.edge_feat + (size_t)g * 16);
#pragma unroll
    for (int q = 0; q < 4; q++) {
      float4 v = efv[q];
      xs[80 + q * 4 + 0][t] = v.x;
      xs[80 + q * 4 + 1][t] = v.y;
      xs[80 + q * 4 + 2][t] = v.z;
      xs[80 + q * 4 + 3][t] = v.w;
    }
  }

  // ---------------- L message-passing layers ----------------
#pragma unroll 1
  for (int l = 0; l < 4; l++) {
    const float* mW1 = p.msg_W1 + l * 576;
    const float* mb1 = p.msg_b1 + l * 16;
    const float* mW2 = p.msg_W2 + l * 256;
    const float* mb2 = p.msg_b2 + l * 16;
    const float* uW1 = p.upd_W1 + l * 512;
    const float* ub1 = p.upd_b1 + l * 16;
    const float* ug1 = p.upd_g1 + l * 5;
    const float* ube1 = p.upd_be1 + l * 5;
    const float* uW2 = p.upd_W2 + l * 256;
    const float* ub2 = p.upd_b2 + l * 16;
    const float* ug2 = p.upd_g2 + l * 5;
    const float* ube2 = p.upd_be2 + l * 5;

    // zero agg rows
#pragma unroll
    for (int r = 0; r < 80; r++) xs[96 + r][t] = 0.f;

    // ---- phase A: per-edge messages, scatter-add into LDS agg rows ----
#pragma unroll 1
    for (int e = 0; e < 8; e++) {
      const int se = __builtin_amdgcn_readfirstlane(p.ei[e]);      // src (SGPR)
      const int de = __builtin_amdgcn_readfirstlane(p.ei[8 + e]);  // dst (SGPR)

      float m1[16];
#pragma unroll
      for (int d = 0; d < 16; d++) m1[d] = mb1[d];

      // h_i = x[dst] part (k = 0..15)
#pragma unroll 4
      for (int k = 0; k < 16; k++) {
        float hv = xs[de * 16 + k][t];
#pragma unroll
        for (int d = 0; d < 16; d++) m1[d] = fmaf(hv, mW1[k * 16 + d], m1[d]);
      }
      // h_j = x[src] part (k = 16..31)
#pragma unroll 4
      for (int k = 0; k < 16; k++) {
        float hv = xs[se * 16 + k][t];
#pragma unroll
        for (int d = 0; d < 16; d++) m1[d] = fmaf(hv, mW1[(16 + k) * 16 + d], m1[d]);
      }
      // ea part (k = 32..35), ea recomputed from raw edge features
      {
        float e0 = xs[80 + e * 2 + 0][t];
        float e1 = xs[80 + e * 2 + 1][t];
#pragma unroll
        for (int j = 0; j < 4; j++) {
          float ea = fmaf(e0, p.W_ee[j], fmaf(e1, p.W_ee[4 + j], p.b_ee[j]));
#pragma unroll
          for (int d = 0; d < 16; d++) m1[d] = fmaf(ea, mW1[(32 + j) * 16 + d], m1[d]);
        }
      }
#pragma unroll
      for (int d = 0; d < 16; d++) m1[d] = sigm(m1[d]);

      // m2 = sigm(m1 @ mW2 + mb2), scatter-add into agg[de] (LDS RMW, runtime row)
#pragma unroll
      for (int d = 0; d < 16; d++) {
        float a = mb2[d];
#pragma unroll
        for (int k = 0; k < 16; k++) a = fmaf(m1[k], mW2[k * 16 + d], a);
        xs[96 + de * 16 + d][t] += sigm(a);
      }
    }

    // ---- phase B: per-node update, x[n] += u2 (in place) ----
#pragma unroll 1
    for (int n = 0; n < 5; n++) {
      float cntf = 0.f;
#pragma unroll
      for (int e = 0; e < 8; e++)
        cntf += (__builtin_amdgcn_readfirstlane(p.ei[8 + e]) == n) ? 1.f : 0.f;
      const float dr = 1.0f / fmaxf(cntf, 1.0f);

      float acc[16];
#pragma unroll
      for (int d = 0; d < 16; d++) acc[d] = ub1[d];
#pragma unroll 4
      for (int k = 0; k < 16; k++) {
        float xv = xs[n * 16 + k][t];
#pragma unroll
        for (int d = 0; d < 16; d++) acc[d] = fmaf(xv, uW1[k * 16 + d], acc[d]);
      }
#pragma unroll 4
      for (int k = 0; k < 16; k++) {
        float av = xs[96 + n * 16 + k][t] * dr;
#pragma unroll
        for (int d = 0; d < 16; d++) acc[d] = fmaf(av, uW1[(16 + k) * 16 + d], acc[d]);
      }
      const float G1 = ug1[n] * INVC;
      const float B1 = ube1[n];
      float u1[16];
#pragma unroll
      for (int d = 0; d < 16; d++) u1[d] = sigm(fmaf(G1, acc[d], B1));

      const float G2 = ug2[n] * INVC;
      const float B2 = ube2[n];
#pragma unroll
      for (int d = 0; d < 16; d++) {
        float a = ub2[d];
#pragma unroll
        for (int k = 0; k < 16; k++) a = fmaf(u1[k], uW2[k * 16 + d], a);
        float u2 = sigm(fmaf(G2, a, B2));
        xs[n * 16 + d][t] += u2;
      }
    }
  }

  // ---------------- pooling: p1 = sigmoid(bnc(x.reshape(80) @ Wp + bp)) ----------------
  float p1[16];
  {
    float acc[16];
#pragma unroll
    for (int d = 0; d < 16; d++) acc[d] = p.bp[d];
#pragma unroll 4
    for (int k = 0; k < 80; k++) {
      float xv = xs[k][t];
#pragma unroll
      for (int d = 0; d < 16; d++) acc[d] = fmaf(xv, p.Wp[k * 16 + d], acc[d]);
    }
#pragma unroll
    for (int d = 0; d < 16; d++)
      p1[d] = sigm(fmaf(p.gp[d] * INVC, acc[d], p.bep[d]));
  }

  // ---------------- MLP head, chunked 16-wide, LDS ping-pong ----------------
  // mlp1: 16 -> 64 (p1 regs -> rows 0..63)
#pragma unroll 1
  for (int c = 0; c < 4; c++) {
    float acc[16];
#pragma unroll
    for (int d = 0; d < 16; d++) acc[d] = p.mb1[c * 16 + d];
#pragma unroll 4
    for (int k = 0; k < 16; k++) {
      float hv = p1[k];
#pragma unroll
      for (int d = 0; d < 16; d++) acc[d] = fmaf(hv, p.mW1[k * 64 + c * 16 + d], acc[d]);
    }
#pragma unroll
    for (int d = 0; d < 16; d++)
      xs[c * 16 + d][t] = sigm(fmaf(p.mg1[c * 16 + d] * INVC, acc[d], p.mbe1[c * 16 + d]));
  }
  // mlp2: 64 -> 64 (rows 0..63 -> rows 96..159)
#pragma unroll 1
  for (int c = 0; c < 4; c++) {
    float acc[16];
#pragma unroll
    for (int d = 0; d < 16; d++) acc[d] = p.mb2[c * 16 + d];
#pragma unroll 4
    for (int k = 0; k < 64; k++) {
      float hv = xs[k][t];
#pragma unroll
      for (int d = 0; d < 16; d++) acc[d] = fmaf(hv, p.mW2[k * 64 + c * 16 + d], acc[d]);
    }
#pragma unroll
    for (int d = 0; d < 16; d++)
      xs[96 + c * 16 + d][t] = sigm(fmaf(p.mg2[c * 16 + d] * INVC, acc[d], p.mbe2[c * 16 + d]));
  }
  // mlp3: 64 -> 64 (rows 96..159 -> rows 0..63)
#pragma unroll 1
  for (int c = 0; c < 4; c++) {
    float acc[16];
#pragma unroll
    for (int d = 0; d < 16; d++) acc[d] = p.mb3[c * 16 + d];
#pragma unroll 4
    for (int k = 0; k < 64; k++) {
      float hv = xs[96 + k][t];
#pragma unroll
      for (int d = 0; d < 16; d++) acc[d] = fmaf(hv, p.mW3[k * 64 + c * 16 + d], acc[d]);
    }
#pragma unroll
    for (int d = 0; d < 16; d++)
      xs[c * 16 + d][t] = sigm(fmaf(p.mg3[c * 16 + d] * INVC, acc[d], p.mbe3[c * 16 + d]));
  }
  // mlp4: 64 -> 1 (rows 0..63 -> out)
  {
    float a = p.mb4[0];
#pragma unroll 4
    for (int k = 0; k < 64; k++) a = fmaf(xs[k][t], p.mW4[k], a);
    p.out[g] = a;
  }
}

extern "C" void kernel_launch(void* const* d_in, const int* in_sizes, int n_in,
                              void* d_out, int out_size, void* d_ws, size_t ws_size,
                              hipStream_t stream) {
  P p;
  p.node_feat = (const float*)d_in[0];
  p.edge_feat = (const float*)d_in[1];
  p.ei        = (const int*)d_in[2];
  p.W_ne  = (const float*)d_in[3];  p.b_ne  = (const float*)d_in[4];
  p.g_ne  = (const float*)d_in[5];  p.be_ne = (const float*)d_in[6];
  p.W_ee  = (const float*)d_in[7];  p.b_ee  = (const float*)d_in[8];
  p.msg_W1 = (const float*)d_in[9];  p.msg_b1 = (const float*)d_in[10];
  p.msg_W2 = (const float*)d_in[11]; p.msg_b2 = (const float*)d_in[12];
  p.upd_W1 = (const float*)d_in[13]; p.upd_b1 = (const float*)d_in[14];
  p.upd_g1 = (const float*)d_in[15]; p.upd_be1 = (const float*)d_in[16];
  p.upd_W2 = (const float*)d_in[17]; p.upd_b2 = (const float*)d_in[18];
  p.upd_g2 = (const float*)d_in[19]; p.upd_be2 = (const float*)d_in[20];
  p.Wp  = (const float*)d_in[21]; p.bp  = (const float*)d_in[22];
  p.gp  = (const float*)d_in[23]; p.bep = (const float*)d_in[24];
  p.mW1 = (const float*)d_in[25]; p.mb1 = (const float*)d_in[26];
  p.mg1 = (const float*)d_in[27]; p.mbe1 = (const float*)d_in[28];
  p.mW2 = (const float*)d_in[29]; p.mb2 = (const float*)d_in[30];
  p.mg2 = (const float*)d_in[31]; p.mbe2 = (const float*)d_in[32];
  p.mW3 = (const float*)d_in[33]; p.mb3 = (const float*)d_in[34];
  p.mg3 = (const float*)d_in[35]; p.mbe3 = (const float*)d_in[36];
  p.mW4 = (const float*)d_in[37]; p.mb4 = (const float*)d_in[38];
  p.out = (float*)d_out;

  hipLaunchKernelGGL(gnn_kernel, dim3(NB / NT), dim3(NT), 0, stream, p);
}